// Round 8
// baseline (449.472 us; speedup 1.0000x reference)
//
#include <hip/hip_runtime.h>
#include <math.h>

#define N 16384
#define KNN 16

typedef __attribute__((ext_vector_type(8))) short bf16x8;
typedef __attribute__((ext_vector_type(4))) float f32x4;
typedef unsigned short ushort_t;
typedef unsigned long long u64;

__device__ __forceinline__ float lrelu(float a) { return a > 0.f ? a : 0.01f * a; }

__device__ __forceinline__ ushort_t f2bf(float f) {
  unsigned u = __float_as_uint(f);
  u += 0x7FFF + ((u >> 16) & 1);
  return (ushort_t)(u >> 16);
}
__device__ __forceinline__ float bf2f(ushort_t h) {
  return __uint_as_float((unsigned)h << 16);
}
__device__ __forceinline__ int lanerank(u64 mask) {
  return __builtin_amdgcn_mbcnt_hi((unsigned)(mask >> 32),
         __builtin_amdgcn_mbcnt_lo((unsigned)mask, 0));
}

// ---------------------------------------------------------------------------
// prepw: fused prep (blocks 0..255) + weight conversion (blocks 256..551).
// ---------------------------------------------------------------------------
#define PPB 64
__global__ __launch_bounds__(256) void prepw_kernel(
    const float* __restrict__ img, const float* __restrict__ cloud,
    const float* __restrict__ p1w, const float* __restrict__ p1b,
    const float* __restrict__ p2w, const float* __restrict__ p2b,
    const float* __restrict__ ps1w, const float* __restrict__ ps2w,
    const float* __restrict__ c1w, const float* __restrict__ c2w,
    float4* __restrict__ pts4, ushort_t* __restrict__ cfh,
    ushort_t* __restrict__ imfh,
    ushort_t* __restrict__ w1h, ushort_t* __restrict__ w2h,
    ushort_t* __restrict__ c1h, ushort_t* __restrict__ c2h) {
  int t = threadIdx.x;
  if (blockIdx.x >= 256) {
    // weight conversion: [0,32768) w1h | [32768,65536) w2h |
    // [65536,67584) c1h | [67584,75776) c2h
    int e = (blockIdx.x - 256) * 256 + t;
    if (e < 32768) w1h[e] = f2bf(ps1w[e]);
    else if (e < 65536) w2h[e - 32768] = f2bf(ps2w[e - 32768]);
    else if (e < 67584) c1h[e - 65536] = f2bf(c1w[e - 65536]);
    else if (e < 75776) c2h[e - 67584] = f2bf(c2w[e - 67584]);
    return;
  }
  __shared__ alignas(16) float w2t[64 * 132];
  __shared__ alignas(16) float hs[PPB * 68];
  __shared__ alignas(16) float w1s[192];
  __shared__ alignas(16) float b1s[64];
  __shared__ alignas(16) float b2s[128];
  __shared__ float ptmp[PPB * 3];
  __shared__ float psx[PPB], psy[PPB], psz[PPB];
  int pb = blockIdx.x * PPB;

  for (int e = t; e < 128 * 64; e += 256) {
    int ch = e >> 6, k = e & 63;
    w2t[k * 132 + ch] = p2w[e];
  }
  if (t < 192) w1s[t] = p1w[t];
  if (t < 64) b1s[t] = p1b[t];
  if (t < 128) b2s[t] = p2b[t];
  if (t < PPB * 3) ptmp[t] = cloud[pb * 3 + t];
  __syncthreads();
  if (t < PPB) {
    float x = ptmp[t * 3], y = ptmp[t * 3 + 1], z = ptmp[t * 3 + 2];
    psx[t] = x; psy[t] = y; psz[t] = z;
    pts4[pb + t] = make_float4(x, y, z, x * x + y * y + z * z);
  }
  for (int e = t; e < 32 * PPB; e += 256) {
    int c = e >> 6, p = e & 63;
    imfh[(size_t)(pb + p) * 32 + c] = f2bf(img[(size_t)c * N + pb + p]);
  }
  __syncthreads();
  for (int e = t; e < PPB * 64; e += 256) {
    int pt_ = e >> 6, ch = e & 63;
    float a = b1s[ch] + psx[pt_] * w1s[ch * 3] + psy[pt_] * w1s[ch * 3 + 1] +
              psz[pt_] * w1s[ch * 3 + 2];
    hs[pt_ * 68 + ch] = lrelu(a);
  }
  __syncthreads();
  for (int e = t; e < PPB * 32; e += 256) {
    int pt_ = e >> 5, c4 = (e & 31) << 2;
    float4 acc = *(const float4*)&b2s[c4];
    const float* hrow = &hs[pt_ * 68];
    #pragma unroll
    for (int k = 0; k < 64; k += 4) {
      float4 h4 = *(const float4*)&hrow[k];
      float4 w0 = *(const float4*)&w2t[(k + 0) * 132 + c4];
      float4 w1_ = *(const float4*)&w2t[(k + 1) * 132 + c4];
      float4 w2_ = *(const float4*)&w2t[(k + 2) * 132 + c4];
      float4 w3 = *(const float4*)&w2t[(k + 3) * 132 + c4];
      acc.x = fmaf(h4.x, w0.x, fmaf(h4.y, w1_.x, fmaf(h4.z, w2_.x, fmaf(h4.w, w3.x, acc.x))));
      acc.y = fmaf(h4.x, w0.y, fmaf(h4.y, w1_.y, fmaf(h4.z, w2_.y, fmaf(h4.w, w3.y, acc.y))));
      acc.z = fmaf(h4.x, w0.z, fmaf(h4.y, w1_.z, fmaf(h4.z, w2_.z, fmaf(h4.w, w3.z, acc.z))));
      acc.w = fmaf(h4.x, w0.w, fmaf(h4.y, w1_.w, fmaf(h4.z, w2_.w, fmaf(h4.w, w3.w, acc.w))));
    }
    unsigned lo = (unsigned)f2bf(acc.x) | ((unsigned)f2bf(acc.y) << 16);
    unsigned hi = (unsigned)f2bf(acc.z) | ((unsigned)f2bf(acc.w) << 16);
    *(uint2*)&cfh[(size_t)(pb + pt_) * 128 + c4] = make_uint2(lo, hi);
  }
}

// ---------------------------------------------------------------------------
// KNN v8: 8 query-waves/block share one TILE=2048 (halves staging + barriers
// per query vs v6); 1 query/wave (minimal selection state); lazy threshold
// with qw folded (d2' = c.w - 2q.c); exact top-16. 40 KB LDS -> 4 blocks/CU.
// ---------------------------------------------------------------------------
__device__ __forceinline__ u64 bsort64(u64 v, int lane) {
  #pragma unroll
  for (int k = 2; k <= 64; k <<= 1) {
    #pragma unroll
    for (int j = k >> 1; j >= 1; j >>= 1) {
      u64 p = __shfl_xor(v, j);
      bool keepmin = (((lane & j) == 0) == ((lane & k) == 0));
      u64 mn = v < p ? v : p;
      u64 mx = v < p ? p : v;
      v = keepmin ? mn : mx;
    }
  }
  return v;
}

__device__ __forceinline__ u64 bclean64(u64 v, int lane) {
  #pragma unroll
  for (int j = 32; j >= 1; j >>= 1) {
    u64 p = __shfl_xor(v, j);
    u64 mn = v < p ? v : p;
    u64 mx = v < p ? p : v;
    v = ((lane & j) == 0) ? mn : mx;
  }
  return v;
}

__device__ __forceinline__ u64 compact_topk(u64* buf, int& cnt, int lane, float& tau) {
  u64 v = (lane < cnt) ? buf[lane] : ~0ULL;
  v = bsort64(v, lane);
  if (cnt > 64) {
    u64 t = (64 + lane < cnt) ? buf[64 + lane] : ~0ULL;
    t = bsort64(t, lane);
    t = __shfl_xor(t, 63);
    v = (t < v) ? t : v;
    v = bclean64(v, lane);
  }
  if (lane < 16) buf[lane] = v;
  cnt = 16;
  u64 k15 = __shfl(v, 15);
  tau = __uint_as_float((unsigned)(k15 >> 32));
  return v;
}

// conservative tau' = tau - qw, padded so the d2' filter never rejects a key
// that the exact key-space test would keep
__device__ __forceinline__ float tadj(float tau, float qw) {
  float a = tau - qw;
  return a + fabsf(a) * 2e-7f + 1e-35f;
}

#define TILE 2048
__global__ __launch_bounds__(512) void knn_kernel(
    const float4* __restrict__ pts4, int* __restrict__ nidx, float* __restrict__ nwgt) {
  __shared__ alignas(16) float4 tile[TILE];  // 32 KB
  __shared__ u64 sbuf[8][128];               // 8 KB
  int t = threadIdx.x;
  int wv = t >> 6, lane = t & 63;
  int wid = blockIdx.x * 8 + wv;
  u64* buf = sbuf[wv];

  float4 q = pts4[wid];
  float q2x = -2.f * q.x, q2y = -2.f * q.y, q2z = -2.f * q.z, qw = q.w;
  float tau, ta;
  int cnt;

  // seed: candidates 0..63 -> sorted -> tight initial tau
  {
    float4 c = pts4[lane];
    float d2 = fmaf(q2x, c.x, fmaf(q2y, c.y, fmaf(q2z, c.z, qw + c.w)));
    u64 v = ((u64)__float_as_uint(fmaxf(d2, 0.f)) << 32) | (unsigned)lane;
    v = bsort64(v, lane);
    if (lane < 16) buf[lane] = v;
    u64 k15 = __shfl(v, 15);
    tau = __uint_as_float((unsigned)(k15 >> 32));
    ta = tadj(tau, qw);
    cnt = 16;
  }

  for (int base = 0; base < N; base += TILE) {
    __syncthreads();
    for (int e = t; e < TILE; e += 512) tile[e] = pts4[base + e];
    __syncthreads();
    for (int s = (base == 0 ? 64 : 0); s < TILE; s += 64) {
      float4 c = tile[s + lane];
      // d2' = c.w - 2 q.c ; true d2 = d2' + qw (added only on rare insert)
      float d2 = fmaf(q2x, c.x, fmaf(q2y, c.y, fmaf(q2z, c.z, c.w)));
      bool pass = (d2 <= ta);
      u64 mask = __ballot(pass);
      if (mask) {
        if (pass) {
          u64 key = ((u64)__float_as_uint(fmaxf(d2 + qw, 0.f)) << 32) |
                    (unsigned)(base + s + lane);
          buf[cnt + lanerank(mask)] = key;
        }
        cnt += __popcll(mask);
        if (cnt > 64) {
          compact_topk(buf, cnt, lane, tau);
          ta = tadj(tau, qw);
        }
      }
    }
  }
  u64 v = compact_topk(buf, cnt, lane, tau);

  // epilogue: lanes 0-15 hold top-16 (ascending by (d2, idx))
  int id = (lane < KNN) ? (int)(unsigned)(v & 0xffffffffULL) : 0;
  float4 c = pts4[id];
  float dx = q.x - c.x, dy = q.y - c.y, dz = q.z - c.z;
  float dist = sqrtf(fmaxf(dx * dx + dy * dy + dz * dz, 1e-12f));
  float md = (lane < KNN) ? dist : INFINITY;
  #pragma unroll
  for (int off = 1; off < KNN; off <<= 1) md = fminf(md, __shfl_xor(md, off));
  float e = expf(md - dist);
  float se = (lane < KNN) ? e : 0.f;
  #pragma unroll
  for (int off = 1; off < KNN; off <<= 1) se += __shfl_xor(se, off);
  if (lane < KNN) {
    nidx[wid * KNN + lane] = id;
    nwgt[wid * KNN + lane] = e / se;
  }
}

// ---------------------------------------------------------------------------
// mega: sf + sfp + final fused per 4 points. LDS region reuse:
//   nb[64x136]bf16 (sfp gather)      -> later reused as feat[4][448] fp32
//   s1[64x264]bf16 (sfp layer1 out)  -> first used as nbi[64x48]+h1[64x72]
// Phases: gather(nb,nbi) | sf l1 -> h1 | sf l2 -> regs | sfp l1 -> s1 |
//         sfp l2 -> regs | feat fill | final GEMV -> out.
// ---------------------------------------------------------------------------
#define NB_LD 136
#define S1_LD 264
#define NI_LD 48
#define H1_LD 72
__global__ __launch_bounds__(256) void mega_kernel(
    const ushort_t* __restrict__ cfh, const ushort_t* __restrict__ imfh,
    const int* __restrict__ nidx, const float* __restrict__ nwgt,
    const ushort_t* __restrict__ w1h, const float* __restrict__ b1,
    const ushort_t* __restrict__ w2h, const float* __restrict__ b2,
    const ushort_t* __restrict__ c1h, const float* __restrict__ c1b,
    const ushort_t* __restrict__ c2h, const float* __restrict__ c2b,
    const float* __restrict__ fw, const float* __restrict__ fb,
    float* __restrict__ out) {
  __shared__ ushort_t nb[64 * NB_LD];   // 17408 B
  __shared__ ushort_t s1[64 * S1_LD];   // 33792 B
  __shared__ int ids[64];
  __shared__ float wg[64];
  ushort_t* nbi = s1;                   // 6144 B
  ushort_t* h1 = s1 + 64 * NI_LD;       // 9216 B (offset 16B-aligned)
  float* feat = (float*)nb;             // 4 x 448 fp32 = 7168 B

  int t = threadIdx.x;
  int w = t >> 6, lane = t & 63;
  int col = lane & 15, quad = lane >> 4;
  int pbase = blockIdx.x * 4;

  if (t < 64) {
    ids[t] = nidx[pbase * 16 + t];
    wg[t] = nwgt[pbase * 16 + t];
  }
  __syncthreads();
  // gather neighbor rows: nb (cfh, 64x128) and nbi (imfh, 64x32)
  for (int e = t; e < 1024; e += 256) {
    int row = e >> 4, c8 = (e & 15) << 3;
    *(uint4*)&nb[row * NB_LD + c8] = *(const uint4*)&cfh[(size_t)ids[row] * 128 + c8];
  }
  {
    int row = t >> 2, c8 = (t & 3) << 3;
    *(uint4*)&nbi[row * NI_LD + c8] = *(const uint4*)&imfh[(size_t)ids[row] * 32 + c8];
  }
  __syncthreads();

  // ---------------- SF layer1: 32 -> 64 (K=32, single step) --------------
  float sfv[2][4];
  {
    f32x4 accA[4];
    #pragma unroll
    for (int p = 0; p < 4; ++p) accA[p] = (f32x4){0.f, 0.f, 0.f, 0.f};
    int n = w * 16 + col;
    bf16x8 b = *(const bf16x8*)&c1h[n * 32 + quad * 8];
    #pragma unroll
    for (int p = 0; p < 4; ++p) {
      bf16x8 a = *(const bf16x8*)&nbi[(p * 16 + col) * NI_LD + quad * 8];
      accA[p] = __builtin_amdgcn_mfma_f32_16x16x32_bf16(a, b, accA[p], 0, 0, 0);
    }
    float bb = c1b[n];
    #pragma unroll
    for (int p = 0; p < 4; ++p)
      #pragma unroll
      for (int r = 0; r < 4; ++r)
        h1[(p * 16 + quad * 4 + r) * H1_LD + n] = f2bf(lrelu(accA[p][r] + bb));
  }
  __syncthreads();
  // ---------------- SF layer2: 64 -> 128 ---------------------------------
  {
    f32x4 acc2[2][4];
    #pragma unroll
    for (int tt = 0; tt < 2; ++tt)
      #pragma unroll
      for (int p = 0; p < 4; ++p) acc2[tt][p] = (f32x4){0.f, 0.f, 0.f, 0.f};
    for (int k0 = 0; k0 < 64; k0 += 32) {
      bf16x8 a[4];
      #pragma unroll
      for (int p = 0; p < 4; ++p)
        a[p] = *(const bf16x8*)&h1[(p * 16 + col) * H1_LD + k0 + quad * 8];
      #pragma unroll
      for (int tt = 0; tt < 2; ++tt) {
        int n = w * 32 + tt * 16 + col;
        bf16x8 b = *(const bf16x8*)&c2h[n * 64 + k0 + quad * 8];
        #pragma unroll
        for (int p = 0; p < 4; ++p)
          acc2[tt][p] = __builtin_amdgcn_mfma_f32_16x16x32_bf16(a[p], b, acc2[tt][p], 0, 0, 0);
      }
    }
    #pragma unroll
    for (int tt = 0; tt < 2; ++tt) {
      int n = w * 32 + tt * 16 + col;
      float bb = c2b[n];
      #pragma unroll
      for (int p = 0; p < 4; ++p) {
        float mx = -INFINITY;
        #pragma unroll
        for (int r = 0; r < 4; ++r)
          mx = fmaxf(mx, (acc2[tt][p][r] + bb) * wg[p * 16 + quad * 4 + r]);
        mx = fmaxf(mx, __shfl_xor(mx, 16));
        mx = fmaxf(mx, __shfl_xor(mx, 32));
        sfv[tt][p] = mx;  // valid on lanes < 16
      }
    }
  }
  __syncthreads();  // h1/nbi dead; s1 region free for sfp layer1 output

  // ---------------- SFP layer1: 128 -> 256 -------------------------------
  {
    f32x4 acc1[4][4];
    #pragma unroll
    for (int tt = 0; tt < 4; ++tt)
      #pragma unroll
      for (int p = 0; p < 4; ++p) acc1[tt][p] = (f32x4){0.f, 0.f, 0.f, 0.f};
    for (int k0 = 0; k0 < 128; k0 += 32) {
      bf16x8 a[4];
      #pragma unroll
      for (int p = 0; p < 4; ++p)
        a[p] = *(const bf16x8*)&nb[(p * 16 + col) * NB_LD + k0 + quad * 8];
      #pragma unroll
      for (int tt = 0; tt < 4; ++tt) {
        int n = w * 64 + tt * 16 + col;
        bf16x8 b = *(const bf16x8*)&w1h[n * 128 + k0 + quad * 8];
        #pragma unroll
        for (int p = 0; p < 4; ++p)
          acc1[tt][p] = __builtin_amdgcn_mfma_f32_16x16x32_bf16(a[p], b, acc1[tt][p], 0, 0, 0);
      }
    }
    #pragma unroll
    for (int tt = 0; tt < 4; ++tt) {
      int n = w * 64 + tt * 16 + col;
      float bb = b1[n];
      #pragma unroll
      for (int p = 0; p < 4; ++p)
        #pragma unroll
        for (int r = 0; r < 4; ++r)
          s1[(p * 16 + quad * 4 + r) * S1_LD + n] = f2bf(lrelu(acc1[tt][p][r] + bb));
    }
  }
  __syncthreads();  // nb dead after this barrier (layer1 reads complete)

  // ---------------- SFP layer2: 256 -> 128 -------------------------------
  float spv[2][4];
  {
    f32x4 acc2[2][4];
    #pragma unroll
    for (int tt = 0; tt < 2; ++tt)
      #pragma unroll
      for (int p = 0; p < 4; ++p) acc2[tt][p] = (f32x4){0.f, 0.f, 0.f, 0.f};
    for (int k0 = 0; k0 < 256; k0 += 32) {
      bf16x8 a[4];
      #pragma unroll
      for (int p = 0; p < 4; ++p)
        a[p] = *(const bf16x8*)&s1[(p * 16 + col) * S1_LD + k0 + quad * 8];
      #pragma unroll
      for (int tt = 0; tt < 2; ++tt) {
        int n = w * 32 + tt * 16 + col;
        bf16x8 b = *(const bf16x8*)&w2h[n * 256 + k0 + quad * 8];
        #pragma unroll
        for (int p = 0; p < 4; ++p)
          acc2[tt][p] = __builtin_amdgcn_mfma_f32_16x16x32_bf16(a[p], b, acc2[tt][p], 0, 0, 0);
      }
    }
    #pragma unroll
    for (int tt = 0; tt < 2; ++tt) {
      int n = w * 32 + tt * 16 + col;
      float bb = b2[n];
      #pragma unroll
      for (int p = 0; p < 4; ++p) {
        float mx = -INFINITY;
        #pragma unroll
        for (int r = 0; r < 4; ++r)
          mx = fmaxf(mx, (acc2[tt][p][r] + bb) * wg[p * 16 + quad * 4 + r]);
        mx = fmaxf(mx, __shfl_xor(mx, 16));
        mx = fmaxf(mx, __shfl_xor(mx, 32));
        spv[tt][p] = mx;  // valid on lanes < 16
      }
    }
  }

  // ---------------- feat fill (into nb region, lrelu applied) ------------
  // layout per point: [0,128) sfp | [128,160) imf | [160,288) sf | [288,416) cf
  #pragma unroll
  for (int tt = 0; tt < 2; ++tt)
    #pragma unroll
    for (int p = 0; p < 4; ++p)
      if (lane < 16) {
        feat[p * 448 + w * 32 + tt * 16 + lane] = lrelu(spv[tt][p]);
        feat[p * 448 + 160 + w * 32 + tt * 16 + lane] = lrelu(sfv[tt][p]);
      }
  if (t < 128) {
    int p = t >> 5, c = t & 31;
    feat[p * 448 + 128 + c] = lrelu(bf2f(imfh[(size_t)(pbase + p) * 32 + c]));
  }
  for (int e = t; e < 512; e += 256) {
    int p = e >> 7, c = e & 127;
    feat[p * 448 + 288 + c] = lrelu(bf2f(cfh[(size_t)(pbase + p) * 128 + c]));
    feat[p * 448 + 416 + (e & 31)] = 0.f;  // pad tail (written redundantly)
  }
  __syncthreads();

  // ---------------- final GEMV: wave w -> point pbase+w -------------------
  {
    int ch = lane & 31, half = lane >> 5;
    float acc = half ? 0.f : fb[ch];
    const float* wr = fw + ch * 416 + half * 208;
    const float* fr = feat + w * 448 + half * 208;
    #pragma unroll 4
    for (int j = 0; j < 208; j += 4) {
      float4 w4 = *(const float4*)(wr + j);
      float4 f4 = *(const float4*)(fr + j);
      acc = fmaf(f4.x, w4.x, fmaf(f4.y, w4.y, fmaf(f4.z, w4.z, fmaf(f4.w, w4.w, acc))));
    }
    acc += __shfl_xor(acc, 32);
    if (lane < 32) out[(size_t)ch * N + pbase + w] = acc;
  }
}

// ---------------------------------------------------------------------------
extern "C" void kernel_launch(void* const* d_in, const int* in_sizes, int n_in,
                              void* d_out, int out_size, void* d_ws, size_t ws_size,
                              hipStream_t stream) {
  const float* img   = (const float*)d_in[0];
  const float* cloud = (const float*)d_in[1];
  const float* c1w   = (const float*)d_in[2];
  const float* c1b   = (const float*)d_in[3];
  const float* c2w   = (const float*)d_in[4];
  const float* c2b   = (const float*)d_in[5];
  const float* ps1w  = (const float*)d_in[6];
  const float* ps1b  = (const float*)d_in[7];
  const float* ps2w  = (const float*)d_in[8];
  const float* ps2b  = (const float*)d_in[9];
  const float* p1w   = (const float*)d_in[10];
  const float* p1b   = (const float*)d_in[11];
  const float* p2w   = (const float*)d_in[12];
  const float* p2b   = (const float*)d_in[13];
  const float* fw    = (const float*)d_in[14];
  const float* fb    = (const float*)d_in[15];
  float* out = (float*)d_out;

  char* ws = (char*)d_ws;
  float4*   pts4 = (float4*)(ws + 0);              // 256 KB
  ushort_t* cfh  = (ushort_t*)(ws + 262144);       // 4 MB
  ushort_t* imfh = (ushort_t*)(ws + 4456448);      // 1 MB
  int*      nidx = (int*)(ws + 5505024);           // 1 MB
  float*    nwgt = (float*)(ws + 6553600);         // 1 MB
  ushort_t* w1h  = (ushort_t*)(ws + 7602176);      // 64 KB
  ushort_t* w2h  = (ushort_t*)(ws + 7667712);      // 64 KB
  ushort_t* c1h  = (ushort_t*)(ws + 7733248);      // 4 KB
  ushort_t* c2h  = (ushort_t*)(ws + 7737344);      // 16 KB

  prepw_kernel<<<552, 256, 0, stream>>>(img, cloud, p1w, p1b, p2w, p2b,
                                        ps1w, ps2w, c1w, c2w,
                                        pts4, cfh, imfh, w1h, w2h, c1h, c2h);
  knn_kernel<<<N / 8, 512, 0, stream>>>(pts4, nidx, nwgt);
  mega_kernel<<<N / 4, 256, 0, stream>>>(cfh, imfh, nidx, nwgt,
                                         w1h, ps1b, w2h, ps2b,
                                         c1h, c1b, c2h, c2b, fw, fb, out);
}